// Round 3
// baseline (108.774 us; speedup 1.0000x reference)
//
#include <hip/hip_runtime.h>
#include <hip/hip_bf16.h>

// CustomBernsteinLayer: out[b,o] = sum_{i,k} ber[b,i,k] * (coeffs[o,i,k]*weights[o,i])
// ber = (1+t)^k (1-t)^(8-k), t = tanh(x).  With e = exp2(2x*log2e):
//   (1-t) = 2/(e+1) = q, ratio r = e, p0 = q^8, ber_{k+1} = ber_k * r.
// bf16 MFMA GEMM M=16384 N=256 K=2304, per-lane in-register A-gen (validated).
// R10: decouple B-reuse from occupancy. R9 (m=4, 1 wave/SIMD) regressed
// +2.1us -> kernel is latency-hiding-bound, not LDS-throughput-bound. Keep
// R9's 4x B-fragment reuse (each ds_read_b128 feeds 4 MFMAs) but restore
// 2 waves/SIMD by shrinking N-extent: 512 blocks x 256 thr (4 waves), block
// owns a 32-col slice (cg=8), wave = 64 rows x 32 cols (m=4, n=2).
// Per-step slice 4 KB -> one global_load_lds round/step; LDS 2x16 KB ->
// 2 blocks/CU, 8 waves/CU. MFMA floor (~9.3us/CU) is now the binding pipe
// with enough waves to hide ds_read latency and barrier drains.

#define BDIM 16384
#define IDIM 256
#define ODIM 256
#define NK 9
#define NCHUNK 4
#define NSTEP 36
#define STEP_ELEMS (ODIM * 64)   // 16384 bf16 (32 KB) per K-step block
#define SLICE 2048               // ushorts per step per 32-col slice (4 KB)

typedef short short8 __attribute__((ext_vector_type(8)));
typedef float floatx4 __attribute__((ext_vector_type(4)));

// ---------------------------------------------------------------------------
// prep (validated): wc[step][e] = bf16(coeffs[o,i,k]*weights[o,i]),
// e = (((o>>4)*2 + s)*64 + (o&15) + quad*16)*8 + j, i_local = s*32+quad*8+j,
// step = (i>>6)*9 + k. One coalesced 16B store per thread.
// ---------------------------------------------------------------------------
__global__ __launch_bounds__(256) void prep_wc2(const float* __restrict__ weights,
                                                const float* __restrict__ coeffs,
                                                ushort* __restrict__ wc) {
    int idx  = blockIdx.x * 256 + threadIdx.x;  // 73728 chunks
    int step = idx >> 11;
    int c    = idx & 2047;
    int big    = c >> 6;
    int lane_w = c & 63;
    int o    = (big >> 1) * 16 + (lane_w & 15);
    int s    = big & 1;
    int quad = lane_w >> 4;
    int ic = step / 9;
    int k  = step - ic * 9;
    int i0 = ic * 64 + s * 32 + quad * 8;

    const float* cp = coeffs + (size_t)(o * IDIM + i0) * NK + k;
    float4 w0 = *(const float4*)(weights + o * IDIM + i0);
    float4 w1 = *(const float4*)(weights + o * IDIM + i0 + 4);
    float wv[8] = {w0.x, w0.y, w0.z, w0.w, w1.x, w1.y, w1.z, w1.w};

    union { ushort us[8]; int4 v; __hip_bfloat162 h2[4]; } pk;
#pragma unroll
    for (int j = 0; j < 8; j += 2) {
        float a = cp[(size_t)j * NK] * wv[j];
        float b = cp[(size_t)(j + 1) * NK] * wv[j + 1];
        pk.h2[j >> 1] = __float22bfloat162_rn(make_float2(a, b));
    }
    *(int4*)(wc + (size_t)step * STEP_ELEMS + (size_t)c * 8) = pk.v;
}

// ---------------------------------------------------------------------------
// GEMM: 512 blocks x 256 threads (4 waves), 2 blocks/CU (32 KB LDS each).
//   cg = blk & 7  -> cols cg*32 .. +31 (whole block)
//   rg = blk >> 3 -> wave w: rows rg*256 + w*64 .. +63 (m=4 tiles of 16)
// Per-lane A state: rows rb + m*16 + (lane&15), m in {0..3};
//   i_local = s*32 + (lane>>4)*8 + j.
// B: 32-col slice of each step is a contiguous 4 KB of wc (big index
// (o>>4)*2+s = cg*4 + n*2 + s, n in {0,1}); groups of 4 steps (16 KB)
// staged into Blds[2][16KB] one group ahead; fragment (n,s) of step g*4+k4
// at Blds[g&1][k4*2048 + (n*2+s)*512 + lane*8], read as b128 and reused
// across all 4 m's.
// ---------------------------------------------------------------------------
__global__ __launch_bounds__(256, 2) void bern_gemm(const float* __restrict__ x,
                                                    const ushort* __restrict__ wc,
                                                    float* __restrict__ out) {
    __shared__ ushort Blds[2][8192];   // 2 x 16 KB

    const int tid  = threadIdx.x;
    const int wave = tid >> 6;          // 0..3
    const int lane = tid & 63;
    const int cg   = blockIdx.x & 7;
    const int rb   = (blockIdx.x >> 3) * 256 + wave * 64;
    const int lrow = lane & 15;
    const int jseg = (lane >> 4) * 8;      // 0,8,16,24

    float p[4][2][8];   // [m][s][j]: running ber
    float r[4][2][8];   // raw x at load time, then ratio e = exp2(2x log2 e)
    floatx4 acc[4][2];
    floatx4 zero = {0.0f, 0.0f, 0.0f, 0.0f};
#pragma unroll
    for (int m = 0; m < 4; ++m)
#pragma unroll
        for (int n = 0; n < 2; ++n)
            acc[m][n] = zero;

    // load raw x for chunk ic_ into r[][][] (r is dead when this runs)
#define LOAD_XR(ic_)                                                            \
    {                                                                           \
        _Pragma("unroll") for (int m = 0; m < 4; ++m)                           \
        _Pragma("unroll") for (int s = 0; s < 2; ++s) {                         \
            const float* xp = x + (size_t)(rb + m * 16 + lrow) * IDIM           \
                              + (ic_) * 64 + s * 32 + jseg;                     \
            float4 v0 = *(const float4*)(xp);                                   \
            float4 v1 = *(const float4*)(xp + 4);                               \
            r[m][s][0] = v0.x; r[m][s][1] = v0.y;                               \
            r[m][s][2] = v0.z; r[m][s][3] = v0.w;                               \
            r[m][s][4] = v1.x; r[m][s][5] = v1.y;                               \
            r[m][s][6] = v1.z; r[m][s][7] = v1.w;                               \
        }                                                                       \
    }

    // r holds raw x -> p = q^8, r = ratio
#define SETUP_FROM_R()                                                          \
    {                                                                           \
        _Pragma("unroll") for (int m = 0; m < 4; ++m)                           \
        _Pragma("unroll") for (int s = 0; s < 2; ++s)                           \
        _Pragma("unroll") for (int e = 0; e < 8; ++e) {                         \
            float t  = __builtin_amdgcn_exp2f(r[m][s][e] * 2.8853900817779268f);\
            float q  = 2.0f * __builtin_amdgcn_rcpf(t + 1.0f);                  \
            float q2 = q * q;                                                   \
            float q4 = q2 * q2;                                                 \
            p[m][s][e] = q4 * q4;                                               \
            r[m][s][e] = t;                                                     \
        }                                                                       \
    }

    // stage group g_ (4 steps, 16 KB slice) into Blds[b_]; 256 threads x 16B
    // cover one step's 4 KB slice per q-round (one global_load_lds each).
#define STAGE(g_, b_)                                                           \
    {                                                                           \
        _Pragma("unroll") for (int q = 0; q < 4; ++q) {                         \
            int st  = (g_) * 4 + q;                                             \
            int off = wave * 512 + lane * 8;                                    \
            const ushort* sp = wc + (size_t)st * STEP_ELEMS + cg * SLICE + off; \
            ushort* dp = &Blds[b_][q * SLICE + off];                            \
            __builtin_amdgcn_global_load_lds(                                   \
                (const __attribute__((address_space(1))) void*)sp,              \
                (__attribute__((address_space(3))) void*)dp, 16, 0, 0);         \
        }                                                                       \
    }

    LOAD_XR(0);
    SETUP_FROM_R();
    STAGE(0, 0);

#pragma unroll
    for (int g = 0; g < 9; ++g) {
        __syncthreads();            // group g resident; prev buf free
        if (g < 8) STAGE(g + 1, (g + 1) & 1);

#pragma unroll
        for (int k4 = 0; k4 < 4; ++k4) {
            const int step = g * 4 + k4;
            // last step of a chunk: issue next chunk's x loads into r[]
            // (r is dead here) so they hide under this step's MFMAs
            if (step == 8 || step == 17 || step == 26) {
                LOAD_XR(step / 9 + 1);
            }
            const int kin = step % 9;

#pragma unroll
            for (int s = 0; s < 2; ++s) {
                // B fragments for this (step, s) from LDS, reused by 4 m's
                short8 bfr[2];
#pragma unroll
                for (int n = 0; n < 2; ++n)
                    bfr[n] = *(const short8*)&Blds[g & 1]
                        [k4 * SLICE + (n * 2 + s) * 512 + lane * 8];

#pragma unroll
                for (int m = 0; m < 4; ++m) {
                    union { ushort us[8]; short8 v; __hip_bfloat162 h2[4]; } pk;
#pragma unroll
                    for (int e = 0; e < 8; e += 2) {
                        pk.h2[e >> 1] = __float22bfloat162_rn(
                            make_float2(p[m][s][e], p[m][s][e + 1]));
                    }
#pragma unroll
                    for (int n = 0; n < 2; ++n)
                        acc[m][n] = __builtin_amdgcn_mfma_f32_16x16x32_bf16(
                            pk.v, bfr[n], acc[m][n], 0, 0, 0);
                    if (kin < NK - 1)
#pragma unroll
                        for (int e = 0; e < 8; ++e) p[m][s][e] *= r[m][s][e];
                }
            }

            // convert the prefetched x (in r) into fresh basis state after
            // this step's MFMAs consumed the old p
            if (step == 8 || step == 17 || step == 26) {
                SETUP_FROM_R();
            }
        }
    }

    // ---- epilogue: C/D layout col=lane&15, row=(lane>>4)*4+reg ----
#pragma unroll
    for (int m = 0; m < 4; ++m) {
#pragma unroll
        for (int n = 0; n < 2; ++n) {
            int col   = cg * 32 + n * 16 + (lane & 15);
            int rbase = rb + m * 16 + (lane >> 4) * 4;
#pragma unroll
            for (int reg = 0; reg < 4; ++reg) {
                out[(size_t)(rbase + reg) * ODIM + col] = acc[m][n][reg];
            }
        }
    }
#undef LOAD_XR
#undef SETUP_FROM_R
#undef STAGE
}

extern "C" void kernel_launch(void* const* d_in, const int* in_sizes, int n_in,
                              void* d_out, int out_size, void* d_ws, size_t ws_size,
                              hipStream_t stream) {
    const float* x       = (const float*)d_in[0];   // [B, I]
    const float* weights = (const float*)d_in[1];   // [O, I]
    const float* coeffs  = (const float*)d_in[2];   // [O, I, 9]
    float* out = (float*)d_out;                     // [B, O]
    ushort* wc = (ushort*)d_ws;                     // 36 * 32 KB = 1.13 MB

    prep_wc2<<<288, 256, 0, stream>>>(weights, coeffs, wc);
    bern_gemm<<<512, 256, 0, stream>>>(x, wc, out);
}

// Round 5
// 97.992 us; speedup vs baseline: 1.1100x; 1.1100x over previous
//
#include <hip/hip_runtime.h>
#include <hip/hip_bf16.h>

// CustomBernsteinLayer: out[b,o] = sum_{i,k} ber[b,i,k] * (coeffs[o,i,k]*weights[o,i])
// ber = (1+t)^k (1-t)^(8-k), t = tanh(x).  With e = exp2(2x*log2e):
//   (1-t) = 2/(e+1) = q, ratio r = e, p0 = q^8, ber_{k+1} = ber_k * r.
// bf16 MFMA GEMM M=16384 N=256 K=2304, per-lane in-register A-gen (validated).
// R12: R11's counted-vmcnt pipeline with the r-clobber bug fixed.
// R11 failed: LOAD_XR at group headers g=1/3/5 overwrote r[] while steps
// kin<8 of the current chunk still needed it (p *= r) -> garbage.
// Fix: dedicated xq[2][2][8] raw-x prefetch buffer (+32 VGPR, fits (512,2)
// budget). Headers g=1/3/5 prefetch next chunk's x into xq (1-2 groups of
// latency cover); SETUP at steps 8/17/26 converts xq -> p,r after that
// step's MFMAs (p,r dead there). Pipeline unchanged from R11: 3x32KB LDS,
// STAGE two groups ahead, raw s_barrier + counted vmcnt (4/12, 0 only at
// g=8), no mid-loop drains.

#define BDIM 16384
#define IDIM 256
#define ODIM 256
#define NK 9
#define NSTEP 36
#define STEP_ELEMS (ODIM * 64)   // 16384 bf16 (32 KB) per K-step block

typedef short short8 __attribute__((ext_vector_type(8)));
typedef float floatx4 __attribute__((ext_vector_type(4)));

// ---------------------------------------------------------------------------
// prep (validated): wc[step][e] = bf16(coeffs[o,i,k]*weights[o,i]),
// e = (((o>>4)*2 + s)*64 + (o&15) + quad*16)*8 + j, i_local = s*32+quad*8+j,
// step = (i>>6)*9 + k. One coalesced 16B store per thread.
// ---------------------------------------------------------------------------
__global__ __launch_bounds__(256) void prep_wc2(const float* __restrict__ weights,
                                                const float* __restrict__ coeffs,
                                                ushort* __restrict__ wc) {
    int idx  = blockIdx.x * 256 + threadIdx.x;  // 73728 chunks
    int step = idx >> 11;
    int c    = idx & 2047;
    int big    = c >> 6;
    int lane_w = c & 63;
    int o    = (big >> 1) * 16 + (lane_w & 15);
    int s    = big & 1;
    int quad = lane_w >> 4;
    int ic = step / 9;
    int k  = step - ic * 9;
    int i0 = ic * 64 + s * 32 + quad * 8;

    const float* cp = coeffs + (size_t)(o * IDIM + i0) * NK + k;
    float4 w0 = *(const float4*)(weights + o * IDIM + i0);
    float4 w1 = *(const float4*)(weights + o * IDIM + i0 + 4);
    float wv[8] = {w0.x, w0.y, w0.z, w0.w, w1.x, w1.y, w1.z, w1.w};

    union { ushort us[8]; int4 v; __hip_bfloat162 h2[4]; } pk;
#pragma unroll
    for (int j = 0; j < 8; j += 2) {
        float a = cp[(size_t)j * NK] * wv[j];
        float b = cp[(size_t)(j + 1) * NK] * wv[j + 1];
        pk.h2[j >> 1] = __float22bfloat162_rn(make_float2(a, b));
    }
    *(int4*)(wc + (size_t)step * STEP_ELEMS + (size_t)c * 8) = pk.v;
}

// ---------------------------------------------------------------------------
// GEMM: 256 blocks x 512 threads (8 waves), 1 block/CU (96 KB LDS).
//   cg = blk & 3  -> cols cg*64 .. +63 (whole block)
//   rg = blk >> 2 -> wave w: rows rg*256 + w*32 .. +31 (m=2 tiles of 16)
// Per-lane A state: rows rb + m*16 + (lane&15), m in {0,1};
//   i_local = s*32 + (lane>>4)*8 + j.
// B: cg-slice of each step is a contiguous 8 KB of wc; groups of 4 steps
// (32 KB) staged into Blds[3] TWO groups ahead via global_load_lds; fragment
// (n,s) of step g*4+k4 at Blds[g%3][k4*4096 + (n*2+s)*512 + lane*8] (b128).
// Raw s_barrier + counted vmcnt per group header; never drains mid-loop.
// ---------------------------------------------------------------------------
__global__ __launch_bounds__(512, 2) void bern_gemm(const float* __restrict__ x,
                                                    const ushort* __restrict__ wc,
                                                    float* __restrict__ out) {
    __shared__ ushort Blds[3][16384];   // 3 x 32 KB

    const int tid  = threadIdx.x;
    const int wave = tid >> 6;          // 0..7
    const int lane = tid & 63;
    const int cg   = blockIdx.x & 3;
    const int rb   = (blockIdx.x >> 2) * 256 + wave * 32;
    const int lrow = lane & 15;
    const int jseg = (lane >> 4) * 8;      // 0,8,16,24

    float p[2][2][8];    // [m][s][j]: running ber
    float r[2][2][8];    // ratio e = exp2(2x log2 e), live all chunk
    float xq[2][2][8];   // raw-x prefetch buffer (filled 1-2 groups early)
    floatx4 acc[2][4];
    floatx4 zero = {0.0f, 0.0f, 0.0f, 0.0f};
#pragma unroll
    for (int m = 0; m < 2; ++m)
#pragma unroll
        for (int n = 0; n < 4; ++n)
            acc[m][n] = zero;

    // load raw x for chunk ic_ into xq (xq is dead when this runs)
#define LOAD_XQ(ic_)                                                            \
    {                                                                           \
        _Pragma("unroll") for (int m = 0; m < 2; ++m)                           \
        _Pragma("unroll") for (int s = 0; s < 2; ++s) {                         \
            const float* xp = x + (size_t)(rb + m * 16 + lrow) * IDIM           \
                              + (ic_) * 64 + s * 32 + jseg;                     \
            float4 v0 = *(const float4*)(xp);                                   \
            float4 v1 = *(const float4*)(xp + 4);                               \
            xq[m][s][0] = v0.x; xq[m][s][1] = v0.y;                             \
            xq[m][s][2] = v0.z; xq[m][s][3] = v0.w;                             \
            xq[m][s][4] = v1.x; xq[m][s][5] = v1.y;                             \
            xq[m][s][6] = v1.z; xq[m][s][7] = v1.w;                             \
        }                                                                       \
    }

    // xq holds raw x -> p = q^8, r = ratio (p,r dead when this runs)
#define SETUP_FROM_XQ()                                                         \
    {                                                                           \
        _Pragma("unroll") for (int m = 0; m < 2; ++m)                           \
        _Pragma("unroll") for (int s = 0; s < 2; ++s)                           \
        _Pragma("unroll") for (int e = 0; e < 8; ++e) {                         \
            float t  = __builtin_amdgcn_exp2f(xq[m][s][e] * 2.8853900817779268f);\
            float q  = 2.0f * __builtin_amdgcn_rcpf(t + 1.0f);                  \
            float q2 = q * q;                                                   \
            float q4 = q2 * q2;                                                 \
            p[m][s][e] = q4 * q4;                                               \
            r[m][s][e] = t;                                                     \
        }                                                                       \
    }

    // stage group g_ (4 steps, 32 KB cg-slice) into Blds[b_]; 512 threads x
    // 16B cover one step's 8 KB slice per q-round (4 loads/thread total).
#define STAGE(g_, b_)                                                           \
    {                                                                           \
        _Pragma("unroll") for (int q = 0; q < 4; ++q) {                         \
            int st  = (g_) * 4 + q;                                             \
            int off = wave * 512 + lane * 8;                                    \
            const ushort* sp = wc + (size_t)st * STEP_ELEMS + cg * 4096 + off;  \
            ushort* dp = &Blds[b_][q * 4096 + off];                             \
            __builtin_amdgcn_global_load_lds(                                   \
                (const __attribute__((address_space(1))) void*)sp,              \
                (__attribute__((address_space(3))) void*)dp, 16, 0, 0);         \
        }                                                                       \
    }

#define WAITV(n_) asm volatile("s_waitcnt vmcnt(" #n_ ")" ::: "memory")

    LOAD_XQ(0);
    SETUP_FROM_XQ();
    STAGE(0, 0);   // 4 loads in flight
    STAGE(1, 1);   // 8 loads in flight

#pragma unroll
    for (int g = 0; g < 9; ++g) {
        // group g resident; stage(g+1) (and possibly 8 x-loads) stay in
        // flight. FIFO math: stage(g)'s 4 loads are always the oldest.
        if (g == 2 || g == 4 || g == 6) { WAITV(12); }
        else if (g == 8)                { WAITV(0);  }
        else                            { WAITV(4);  }
        __builtin_amdgcn_s_barrier();
        __builtin_amdgcn_sched_barrier(0);

        // chunk-boundary x prefetch into xq (dead), BEFORE the stage loads
        // so they're older in the vmcnt FIFO; consumed at steps 8/17/26.
        if (g == 1) LOAD_XQ(1);
        if (g == 3) LOAD_XQ(2);
        if (g == 5) LOAD_XQ(3);
        if (g < 7) STAGE(g + 2, (g + 2) % 3);

        const int bg = g % 3;
#pragma unroll
        for (int k4 = 0; k4 < 4; ++k4) {
            const int step = g * 4 + k4;
            const int kin = step % 9;

#pragma unroll
            for (int s = 0; s < 2; ++s) {
                // B fragments for this (step, s) from LDS, reused by 2 m's
                short8 bfr[4];
#pragma unroll
                for (int n = 0; n < 4; ++n)
                    bfr[n] = *(const short8*)&Blds[bg]
                        [k4 * 4096 + (n * 2 + s) * 512 + lane * 8];

#pragma unroll
                for (int m = 0; m < 2; ++m) {
                    union { ushort us[8]; short8 v; __hip_bfloat162 h2[4]; } pk;
#pragma unroll
                    for (int e = 0; e < 8; e += 2) {
                        pk.h2[e >> 1] = __float22bfloat162_rn(
                            make_float2(p[m][s][e], p[m][s][e + 1]));
                    }
#pragma unroll
                    for (int n = 0; n < 4; ++n)
                        acc[m][n] = __builtin_amdgcn_mfma_f32_16x16x32_bf16(
                            pk.v, bfr[n], acc[m][n], 0, 0, 0);
                    if (kin < NK - 1)
#pragma unroll
                        for (int e = 0; e < 8; ++e) p[m][s][e] *= r[m][s][e];
                }
            }

            // chunk boundary (kin==8): old p,r now dead; build next chunk's
            // basis from the prefetched xq (compiler emits its own counted
            // vmcnt for the xq loads; stage loads issued after stay in flight)
            if (step == 8 || step == 17 || step == 26) {
                SETUP_FROM_XQ();
            }
        }
    }

    // ---- epilogue: C/D layout col=lane&15, row=(lane>>4)*4+reg ----
#pragma unroll
    for (int m = 0; m < 2; ++m) {
#pragma unroll
        for (int n = 0; n < 4; ++n) {
            int col   = cg * 64 + n * 16 + (lane & 15);
            int rbase = rb + m * 16 + (lane >> 4) * 4;
#pragma unroll
            for (int reg = 0; reg < 4; ++reg) {
                out[(size_t)(rbase + reg) * ODIM + col] = acc[m][n][reg];
            }
        }
    }
#undef LOAD_XQ
#undef SETUP_FROM_XQ
#undef STAGE
#undef WAITV
}

extern "C" void kernel_launch(void* const* d_in, const int* in_sizes, int n_in,
                              void* d_out, int out_size, void* d_ws, size_t ws_size,
                              hipStream_t stream) {
    const float* x       = (const float*)d_in[0];   // [B, I]
    const float* weights = (const float*)d_in[1];   // [O, I]
    const float* coeffs  = (const float*)d_in[2];   // [O, I, 9]
    float* out = (float*)d_out;                     // [B, O]
    ushort* wc = (ushort*)d_ws;                     // 36 * 32 KB = 1.13 MB

    prep_wc2<<<288, 256, 0, stream>>>(weights, coeffs, wc);
    bern_gemm<<<256, 512, 0, stream>>>(x, wc, out);
}